// Round 1
// baseline (1620.999 us; speedup 1.0000x reference)
//
#include <hip/hip_runtime.h>
#include <cstdint>
#include <cstddef>

#define N_NODES 100000
#define DIM     64
#define N_EDGES 1600000
#define BATCH   8192
#define NP      262144
#define INV_T   2.0f        // 1/T, T=0.5
#define LAM_REG 1e-4f

#define SCAN_CHUNK 1024
#define NB_SCAN ((N_NODES + SCAN_CHUNK - 1) / SCAN_CHUNK)   // 98

static __device__ __forceinline__ float waveSum(float v) {
#pragma unroll
    for (int off = 32; off > 0; off >>= 1) v += __shfl_xor(v, off, 64);
    return v;
}

// ---------------- CSR build ----------------
__global__ void k_hist(const int* __restrict__ erow, int* __restrict__ counts, int e) {
    int i = blockIdx.x * blockDim.x + threadIdx.x;
    if (i < e) atomicAdd(&counts[erow[i]], 1);
}

__global__ void k_scan1(const int* __restrict__ counts, int* __restrict__ rowptr,
                        int* __restrict__ bsums, int n) {
    __shared__ int tmp[SCAN_CHUNK];
    int gid = blockIdx.x * SCAN_CHUNK + threadIdx.x;
    int v = (gid < n) ? counts[gid] : 0;
    tmp[threadIdx.x] = v;
    __syncthreads();
    for (int off = 1; off < SCAN_CHUNK; off <<= 1) {
        int t = (threadIdx.x >= off) ? tmp[threadIdx.x - off] : 0;
        __syncthreads();
        tmp[threadIdx.x] += t;
        __syncthreads();
    }
    if (gid < n) rowptr[gid] = tmp[threadIdx.x] - v;   // exclusive
    if (threadIdx.x == SCAN_CHUNK - 1) bsums[blockIdx.x] = tmp[threadIdx.x];
}

__global__ void k_scan2(int* __restrict__ bsums, int nb, int* __restrict__ rowptr,
                        int n, int total) {
    __shared__ int tmp[128];
    int v = (threadIdx.x < nb) ? bsums[threadIdx.x] : 0;
    tmp[threadIdx.x] = v;
    __syncthreads();
    for (int off = 1; off < 128; off <<= 1) {
        int t = (threadIdx.x >= off) ? tmp[threadIdx.x - off] : 0;
        __syncthreads();
        tmp[threadIdx.x] += t;
        __syncthreads();
    }
    if (threadIdx.x < nb) bsums[threadIdx.x] = tmp[threadIdx.x] - v;   // exclusive
    if (threadIdx.x == 0) rowptr[n] = total;
}

__global__ void k_scan3(int* __restrict__ rowptr, const int* __restrict__ bsums, int n) {
    int gid = blockIdx.x * SCAN_CHUNK + threadIdx.x;
    if (gid < n) rowptr[gid] += bsums[blockIdx.x];
}

__global__ void k_scatter(const int* __restrict__ erow, const int* __restrict__ ecol,
                          const float* __restrict__ v1, const float* __restrict__ v2,
                          const float* __restrict__ v0,
                          const int* __restrict__ rowptr, int* __restrict__ cursor,
                          int* __restrict__ ccol, float* __restrict__ cv1,
                          float* __restrict__ cv2, float* __restrict__ cv0, int e) {
    int i = blockIdx.x * blockDim.x + threadIdx.x;
    if (i >= e) return;
    int r = erow[i];
    int p = rowptr[r] + atomicAdd(&cursor[r], 1);
    ccol[p] = ecol[i];
    cv1[p] = v1[i];
    cv2[p] = v2[i];
    cv0[p] = v0[i];
}

// ---------------- propagation: one wave per node, lane = dim ----------------
__global__ void k_prop(const int* __restrict__ rowptr, const int* __restrict__ ccol,
                       const float* __restrict__ cval, const float* __restrict__ cur,
                       float* __restrict__ nxt, int n) {
    int wid = (blockIdx.x * blockDim.x + threadIdx.x) >> 6;
    int lane = threadIdx.x & 63;
    if (wid >= n) return;
    int node = __builtin_amdgcn_readfirstlane(wid);
    int s = rowptr[node];
    int e = rowptr[node + 1];
    float acc = 0.f;
    for (int k = s; k < e; ++k) {
        int c = ccol[k];
        float w = cval[k];
        acc += w * cur[(size_t)c * DIM + lane];
    }
    nxt[(size_t)node * DIM + lane] = acc;
}

__global__ void k_addfull(float* __restrict__ acc, const float* __restrict__ x, int n4) {
    int stride = gridDim.x * blockDim.x;
    for (int i = blockIdx.x * blockDim.x + threadIdx.x; i < n4; i += stride) {
        float4 a = ((const float4*)acc)[i];
        float4 b = ((const float4*)x)[i];
        a.x += b.x; a.y += b.y; a.z += b.z; a.w += b.w;
        ((float4*)acc)[i] = a;
    }
}

__global__ void k_gather(const int* __restrict__ nodes, const float* __restrict__ src,
                         float* __restrict__ dst, int nb, int add) {
    int t = blockIdx.x * blockDim.x + threadIdx.x;
    int w = t >> 6, lane = t & 63;
    if (w >= nb) return;
    int nd = nodes[w];
    float v = src[(size_t)nd * DIM + lane];
    if (add) dst[(size_t)w * DIM + lane] += v;
    else     dst[(size_t)w * DIM + lane] = v;
}

// ---------------- SSL ----------------
__global__ void k_norm(const float* __restrict__ e1, const float* __restrict__ e2,
                       float* __restrict__ n1, float* __restrict__ n2,
                       float* __restrict__ pos, int nb) {
    int t = blockIdx.x * blockDim.x + threadIdx.x;
    int w = t >> 6, lane = t & 63;
    if (w >= nb) return;
    float a = e1[(size_t)w * DIM + lane];
    float b = e2[(size_t)w * DIM + lane];
    float sa = waveSum(fabsf(a));
    float sb = waveSum(fabsf(b));
    float na = a / fmaxf(sa, 1e-12f);
    float nb2 = b / fmaxf(sb, 1e-12f);
    n1[(size_t)w * DIM + lane] = na;
    n2[(size_t)w * DIM + lane] = nb2;
    float p = waveSum(na * nb2);
    if (lane == 0) pos[w] = p;
}

#define SSL_SLICES 16
#define SSL_TJ 64
__global__ __launch_bounds__(256) void k_ssl(const float* __restrict__ n1,
                                             const float* __restrict__ n2,
                                             float* __restrict__ ttl) {
    __shared__ float tile[SSL_TJ * DIM];
    int ib = blockIdx.x & 31;   // 32 i-blocks of 256
    int js = blockIdx.x >> 5;   // 16 j-slices of 512
    int tid = threadIdx.x;
    int i = ib * 256 + tid;
    float r[DIM];
#pragma unroll
    for (int d = 0; d < DIM; ++d) r[d] = n1[(size_t)i * DIM + d];
    float sumexp = 0.f;
    int j0 = js * (BATCH / SSL_SLICES);
    for (int jt = 0; jt < (BATCH / SSL_SLICES); jt += SSL_TJ) {
        const float4* gsrc = (const float4*)(n2 + (size_t)(j0 + jt) * DIM);
        float4* lds4 = (float4*)tile;
        __syncthreads();
#pragma unroll
        for (int q = 0; q < (SSL_TJ * DIM / 4) / 256; ++q)
            lds4[tid + q * 256] = gsrc[tid + q * 256];
        __syncthreads();
        for (int jj = 0; jj < SSL_TJ; ++jj) {
            const float* row = &tile[jj * DIM];
            float s0 = 0.f, s1 = 0.f, s2 = 0.f, s3 = 0.f;
#pragma unroll
            for (int d = 0; d < DIM; d += 4) {
                s0 += r[d]     * row[d];
                s1 += r[d + 1] * row[d + 1];
                s2 += r[d + 2] * row[d + 2];
                s3 += r[d + 3] * row[d + 3];
            }
            float dot = (s0 + s1) + (s2 + s3);
            sumexp += __expf(dot * INV_T);
        }
    }
    atomicAdd(&ttl[i], sumexp);
}

__global__ void k_sslfin(const float* __restrict__ ttl, const float* __restrict__ pos,
                         float* __restrict__ accums) {
    int i = blockIdx.x * blockDim.x + threadIdx.x;
    float v = logf(ttl[i]) - pos[i] * INV_T;
    v = waveSum(v);
    __shared__ float red[4];
    int lane = threadIdx.x & 63, w = threadIdx.x >> 6;
    if (lane == 0) red[w] = v;
    __syncthreads();
    if (threadIdx.x == 0) atomicAdd(&accums[0], red[0] + red[1] + red[2] + red[3]);
}

// ---------------- BPR ----------------
__global__ void k_bpr(const float* __restrict__ accFull, const float* __restrict__ emb,
                      const int* __restrict__ nl, const int* __restrict__ pl,
                      const int* __restrict__ ngl, float* __restrict__ accums, int p) {
    int lane = threadIdx.x & 63;
    int winb = threadIdx.x >> 6;
    int wg = blockIdx.x * (blockDim.x >> 6) + winb;
    int nw = gridDim.x * (blockDim.x >> 6);
    float bprsum = 0.f, regsum = 0.f;
    for (int t = wg; t < p; t += nw) {
        int a = nl[t], b = pl[t], c = ngl[t];
        float u  = accFull[(size_t)a * DIM + lane];
        float v  = accFull[(size_t)b * DIM + lane];
        float g  = accFull[(size_t)c * DIM + lane];
        float u0 = emb[(size_t)a * DIM + lane];
        float v0 = emb[(size_t)b * DIM + lane];
        float n0 = emb[(size_t)c * DIM + lane];
        float posd = waveSum(u * v) * (1.0f / 16.0f);   // fold the (1/4)^2 layer-mean
        float negd = waveSum(u * g) * (1.0f / 16.0f);
        float rg   = waveSum(u0 * u0 + v0 * v0 + n0 * n0);
        float x = negd - posd;
        float sp = fmaxf(x, 0.f) + log1pf(__expf(-fabsf(x)));
        bprsum += sp;
        regsum += rg;
    }
    if (lane == 0) {
        atomicAdd(&accums[1], bprsum);
        atomicAdd(&accums[2], regsum);
    }
}

__global__ void k_final(const float* __restrict__ accums, float* __restrict__ out) {
    if (threadIdx.x == 0 && blockIdx.x == 0) {
        float ssl = accums[0];
        float bpr = accums[1] * (1.0f / (float)NP);
        float reg = 0.5f * accums[2] * (1.0f / (float)BATCH);
        out[0] = ssl + bpr + LAM_REG * reg;
    }
}

// ---------------- launch ----------------
extern "C" void kernel_launch(void* const* d_in, const int* in_sizes, int n_in,
                              void* d_out, int out_size, void* d_ws, size_t ws_size,
                              hipStream_t stream) {
    (void)in_sizes; (void)n_in; (void)out_size; (void)ws_size;
    const float* emb   = (const float*)d_in[0];
    const float* vals1 = (const float*)d_in[1];
    const float* vals2 = (const float*)d_in[2];
    const float* vals0 = (const float*)d_in[3];
    const int* erow    = (const int*)d_in[4];
    const int* ecol    = (const int*)d_in[5];
    const int* nodes   = (const int*)d_in[6];
    const int* nl      = (const int*)d_in[7];
    const int* pl      = (const int*)d_in[8];
    const int* ngl     = (const int*)d_in[9];
    float* out = (float*)d_out;

    char* w = (char*)d_ws;
    size_t off = 0;
    auto alloc = [&](size_t bytes) -> void* {
        void* p = w + off;
        off = (off + bytes + 255) & ~(size_t)255;
        return p;
    };
    int*   counts  = (int*)alloc((size_t)N_NODES * 4);
    int*   rowptr  = (int*)alloc((size_t)(N_NODES + 1) * 4);
    int*   bsums   = (int*)alloc(512);
    int*   ccol    = (int*)alloc((size_t)N_EDGES * 4);
    float* cv1     = (float*)alloc((size_t)N_EDGES * 4);
    float* cv2     = (float*)alloc((size_t)N_EDGES * 4);
    float* cv0     = (float*)alloc((size_t)N_EDGES * 4);
    float* bufA    = (float*)alloc((size_t)N_NODES * DIM * 4);
    float* bufB    = (float*)alloc((size_t)N_NODES * DIM * 4);
    float* accFull = (float*)alloc((size_t)N_NODES * DIM * 4);
    float* accB1   = (float*)alloc((size_t)BATCH * DIM * 4);
    float* accB2   = (float*)alloc((size_t)BATCH * DIM * 4);
    float* n1      = (float*)alloc((size_t)BATCH * DIM * 4);
    float* n2      = (float*)alloc((size_t)BATCH * DIM * 4);
    float* pos     = (float*)alloc((size_t)BATCH * 4);
    float* ttl     = (float*)alloc((size_t)BATCH * 4);
    float* accums  = (float*)alloc(256);

    // zero what is read-modified
    hipMemsetAsync(counts, 0, (size_t)N_NODES * 4, stream);
    hipMemsetAsync(ttl, 0, (size_t)BATCH * 4, stream);
    hipMemsetAsync(accums, 0, 256, stream);

    // CSR build
    k_hist<<<N_EDGES / 256, 256, 0, stream>>>(erow, counts, N_EDGES);
    k_scan1<<<NB_SCAN, SCAN_CHUNK, 0, stream>>>(counts, rowptr, bsums, N_NODES);
    k_scan2<<<1, 128, 0, stream>>>(bsums, NB_SCAN, rowptr, N_NODES, N_EDGES);
    k_scan3<<<NB_SCAN, SCAN_CHUNK, 0, stream>>>(rowptr, bsums, N_NODES);
    hipMemsetAsync(counts, 0, (size_t)N_NODES * 4, stream);
    k_scatter<<<N_EDGES / 256, 256, 0, stream>>>(erow, ecol, vals1, vals2, vals0,
                                                 rowptr, counts, ccol, cv1, cv2, cv0,
                                                 N_EDGES);

    const int propGrid = (N_NODES + 3) / 4;   // 4 waves/block
    const int gGrid = BATCH / 4;              // gather: 4 waves/block

    // view 1 (vals1) -> accB1 at batch nodes
    k_gather<<<gGrid, 256, 0, stream>>>(nodes, emb, accB1, BATCH, 0);
    k_prop<<<propGrid, 256, 0, stream>>>(rowptr, ccol, cv1, emb, bufA, N_NODES);
    k_gather<<<gGrid, 256, 0, stream>>>(nodes, bufA, accB1, BATCH, 1);
    k_prop<<<propGrid, 256, 0, stream>>>(rowptr, ccol, cv1, bufA, bufB, N_NODES);
    k_gather<<<gGrid, 256, 0, stream>>>(nodes, bufB, accB1, BATCH, 1);
    k_prop<<<propGrid, 256, 0, stream>>>(rowptr, ccol, cv1, bufB, bufA, N_NODES);
    k_gather<<<gGrid, 256, 0, stream>>>(nodes, bufA, accB1, BATCH, 1);

    // view 2 (vals2) -> accB2
    k_gather<<<gGrid, 256, 0, stream>>>(nodes, emb, accB2, BATCH, 0);
    k_prop<<<propGrid, 256, 0, stream>>>(rowptr, ccol, cv2, emb, bufA, N_NODES);
    k_gather<<<gGrid, 256, 0, stream>>>(nodes, bufA, accB2, BATCH, 1);
    k_prop<<<propGrid, 256, 0, stream>>>(rowptr, ccol, cv2, bufA, bufB, N_NODES);
    k_gather<<<gGrid, 256, 0, stream>>>(nodes, bufB, accB2, BATCH, 1);
    k_prop<<<propGrid, 256, 0, stream>>>(rowptr, ccol, cv2, bufB, bufA, N_NODES);
    k_gather<<<gGrid, 256, 0, stream>>>(nodes, bufA, accB2, BATCH, 1);

    // base graph (vals0) -> accFull (un-divided; /16 folded into BPR dots)
    hipMemcpyAsync(accFull, emb, (size_t)N_NODES * DIM * 4, hipMemcpyDeviceToDevice,
                   stream);
    k_prop<<<propGrid, 256, 0, stream>>>(rowptr, ccol, cv0, emb, bufA, N_NODES);
    k_addfull<<<2048, 256, 0, stream>>>(accFull, bufA, N_NODES * DIM / 4);
    k_prop<<<propGrid, 256, 0, stream>>>(rowptr, ccol, cv0, bufA, bufB, N_NODES);
    k_addfull<<<2048, 256, 0, stream>>>(accFull, bufB, N_NODES * DIM / 4);
    k_prop<<<propGrid, 256, 0, stream>>>(rowptr, ccol, cv0, bufB, bufA, N_NODES);
    k_addfull<<<2048, 256, 0, stream>>>(accFull, bufA, N_NODES * DIM / 4);

    // SSL
    k_norm<<<gGrid, 256, 0, stream>>>(accB1, accB2, n1, n2, pos, BATCH);
    k_ssl<<<32 * SSL_SLICES, 256, 0, stream>>>(n1, n2, ttl);
    k_sslfin<<<BATCH / 256, 256, 0, stream>>>(ttl, pos, accums);

    // BPR + reg
    k_bpr<<<2048, 256, 0, stream>>>(accFull, emb, nl, pl, ngl, accums, NP);

    k_final<<<1, 64, 0, stream>>>(accums, out);
}

// Round 2
// 785.361 us; speedup vs baseline: 2.0640x; 2.0640x over previous
//
#include <hip/hip_runtime.h>
#include <cstdint>
#include <cstddef>

#define N_NODES 100000
#define DIM     64
#define N_EDGES 1600000
#define BATCH   8192
#define NP      262144
#define INV_T   2.0f        // 1/T, T=0.5
#define LAM_REG 1e-4f

#define SCAN_CHUNK 1024
#define NB_SCAN ((N_NODES + SCAN_CHUNK - 1) / SCAN_CHUNK)   // 98

typedef unsigned int   uint32;
typedef unsigned short u16;
typedef __attribute__((ext_vector_type(4))) float f32x4;
typedef __attribute__((ext_vector_type(8))) short s16x8;

static __device__ __forceinline__ uint32 f2bf(float x) {
    uint32 b = __float_as_uint(x);
    return (b + 0x7fffu + ((b >> 16) & 1u)) >> 16;   // rne, low 16 bits
}
static __device__ __forceinline__ float bfLo(uint32 u) { return __uint_as_float(u << 16); }
static __device__ __forceinline__ float bfHi(uint32 u) { return __uint_as_float(u & 0xffff0000u); }

static __device__ __forceinline__ float waveSum(float v) {
#pragma unroll
    for (int off = 32; off > 0; off >>= 1) v += __shfl_xor(v, off, 64);
    return v;
}

// ---------------- CSR build ----------------
__global__ void k_hist(const int* __restrict__ erow, int* __restrict__ counts, int e) {
    int i = blockIdx.x * blockDim.x + threadIdx.x;
    if (i < e) atomicAdd(&counts[erow[i]], 1);
}

__global__ void k_scan1(const int* __restrict__ counts, int* __restrict__ rowptr,
                        int* __restrict__ bsums, int n) {
    __shared__ int tmp[SCAN_CHUNK];
    int gid = blockIdx.x * SCAN_CHUNK + threadIdx.x;
    int v = (gid < n) ? counts[gid] : 0;
    tmp[threadIdx.x] = v;
    __syncthreads();
    for (int off = 1; off < SCAN_CHUNK; off <<= 1) {
        int t = (threadIdx.x >= off) ? tmp[threadIdx.x - off] : 0;
        __syncthreads();
        tmp[threadIdx.x] += t;
        __syncthreads();
    }
    if (gid < n) rowptr[gid] = tmp[threadIdx.x] - v;   // exclusive
    if (threadIdx.x == SCAN_CHUNK - 1) bsums[blockIdx.x] = tmp[threadIdx.x];
}

__global__ void k_scan2(int* __restrict__ bsums, int nb, int* __restrict__ rowptr,
                        int n, int total) {
    __shared__ int tmp[128];
    int v = (threadIdx.x < nb) ? bsums[threadIdx.x] : 0;
    tmp[threadIdx.x] = v;
    __syncthreads();
    for (int off = 1; off < 128; off <<= 1) {
        int t = (threadIdx.x >= off) ? tmp[threadIdx.x - off] : 0;
        __syncthreads();
        tmp[threadIdx.x] += t;
        __syncthreads();
    }
    if (threadIdx.x < nb) bsums[threadIdx.x] = tmp[threadIdx.x] - v;
    if (threadIdx.x == 0) rowptr[n] = total;
}

__global__ void k_scan3(int* __restrict__ rowptr, const int* __restrict__ bsums, int n) {
    int gid = blockIdx.x * SCAN_CHUNK + threadIdx.x;
    if (gid < n) rowptr[gid] += bsums[blockIdx.x];
}

// scatter edges into CSR; weights converted to bf16 (w1|w2 packed, w0 separate)
__global__ void k_scatter(const int* __restrict__ erow, const int* __restrict__ ecol,
                          const float* __restrict__ v1, const float* __restrict__ v2,
                          const float* __restrict__ v0,
                          const int* __restrict__ rowptr, int* __restrict__ cursor,
                          int* __restrict__ ccol, uint32* __restrict__ cw12,
                          u16* __restrict__ cw0, int e) {
    int i = blockIdx.x * blockDim.x + threadIdx.x;
    if (i >= e) return;
    int r = erow[i];
    int p = rowptr[r] + atomicAdd(&cursor[r], 1);
    ccol[p] = ecol[i];
    cw12[p] = f2bf(v1[i]) | (f2bf(v2[i]) << 16);
    cw0[p] = (u16)f2bf(v0[i]);
}

// fp32 [n][64] -> packed bf16 pairs [n][32]
__global__ void k_cvtbf(const float* __restrict__ src, uint32* __restrict__ dst, int n32) {
    int i = blockIdx.x * blockDim.x + threadIdx.x;
    if (i < n32) {
        float2 v = ((const float2*)src)[i];
        dst[i] = f2bf(v.x) | (f2bf(v.y) << 16);
    }
}

// ---------------- propagation: one wave per node, lane = dim, bf16 gathers ----
__global__ __launch_bounds__(256) void k_prop_l1(
    const int* __restrict__ rowptr, const int* __restrict__ ccol,
    const uint32* __restrict__ cw12, const u16* __restrict__ cw0,
    const u16* __restrict__ ebf, const float* __restrict__ emb,
    u16* __restrict__ o1, u16* __restrict__ o2, u16* __restrict__ o0,
    float* __restrict__ accF, int n) {
    int t = blockIdx.x * blockDim.x + threadIdx.x;
    int node = t >> 6, lane = t & 63;
    if (node >= n) return;
    int s = rowptr[node], e = rowptr[node + 1];
    float a1 = 0.f, a2 = 0.f, a0 = 0.f;
    for (int k = s; k < e; k += 64) {
        int c = 0; uint32 w12 = 0; uint32 w0 = 0;
        int kl = k + lane;
        if (kl < e) { c = ccol[kl]; w12 = cw12[kl]; w0 = cw0[kl]; }
        int cnt = min(64, e - k);
        for (int j = 0; j < cnt; ++j) {
            int cc = __shfl(c, j, 64);
            uint32 ww = (uint32)__shfl((int)w12, j, 64);
            uint32 w0w = (uint32)__shfl((int)w0, j, 64);
            float x = bfLo((uint32)ebf[(size_t)cc * DIM + lane]);
            a1 += bfLo(ww) * x;
            a2 += bfHi(ww) * x;
            a0 += bfLo(w0w) * x;
        }
    }
    size_t off = (size_t)node * DIM + lane;
    o1[off] = (u16)f2bf(a1);
    o2[off] = (u16)f2bf(a2);
    o0[off] = (u16)f2bf(a0);
    accF[off] = emb[off] + a0;
}

__global__ __launch_bounds__(256) void k_prop_l23(
    const int* __restrict__ rowptr, const int* __restrict__ ccol,
    const uint32* __restrict__ cw12, const u16* __restrict__ cw0,
    const u16* __restrict__ t1, const u16* __restrict__ t2, const u16* __restrict__ t0,
    u16* __restrict__ o1, u16* __restrict__ o2, u16* __restrict__ o0,
    float* __restrict__ accF, int n) {
    int t = blockIdx.x * blockDim.x + threadIdx.x;
    int node = t >> 6, lane = t & 63;
    if (node >= n) return;
    int s = rowptr[node], e = rowptr[node + 1];
    float a1 = 0.f, a2 = 0.f, a0 = 0.f;
    for (int k = s; k < e; k += 64) {
        int c = 0; uint32 w12 = 0; uint32 w0 = 0;
        int kl = k + lane;
        if (kl < e) { c = ccol[kl]; w12 = cw12[kl]; w0 = cw0[kl]; }
        int cnt = min(64, e - k);
        for (int j = 0; j < cnt; ++j) {
            int cc = __shfl(c, j, 64);
            uint32 ww = (uint32)__shfl((int)w12, j, 64);
            uint32 w0w = (uint32)__shfl((int)w0, j, 64);
            size_t rb = (size_t)cc * DIM + lane;
            float x1 = bfLo((uint32)t1[rb]);
            float x2 = bfLo((uint32)t2[rb]);
            float x0 = bfLo((uint32)t0[rb]);
            a1 += bfLo(ww) * x1;
            a2 += bfHi(ww) * x2;
            a0 += bfLo(w0w) * x0;
        }
    }
    size_t off = (size_t)node * DIM + lane;
    o1[off] = (u16)f2bf(a1);
    o2[off] = (u16)f2bf(a2);
    o0[off] = (u16)f2bf(a0);
    accF[off] += a0;
}

// gather batch rows of both views; init also adds emb
__global__ void k_gatherB(const int* __restrict__ nodes, const u16* __restrict__ t1,
                          const u16* __restrict__ t2, float* __restrict__ accB1,
                          float* __restrict__ accB2, const float* __restrict__ emb,
                          int init) {
    int t = blockIdx.x * blockDim.x + threadIdx.x;
    int b = t >> 6, lane = t & 63;
    if (b >= BATCH) return;
    int nd = nodes[b];
    size_t src = (size_t)nd * DIM + lane;
    size_t off = (size_t)b * DIM + lane;
    float x1 = bfLo((uint32)t1[src]);
    float x2 = bfLo((uint32)t2[src]);
    if (init) {
        float em = emb[src];
        accB1[off] = em + x1;
        accB2[off] = em + x2;
    } else {
        accB1[off] += x1;
        accB2[off] += x2;
    }
}

// ---------------- SSL ----------------
__global__ void k_norm(const float* __restrict__ e1, const float* __restrict__ e2,
                       u16* __restrict__ n1b, u16* __restrict__ n2b,
                       float* __restrict__ pos, int nb) {
    int t = blockIdx.x * blockDim.x + threadIdx.x;
    int w = t >> 6, lane = t & 63;
    if (w >= nb) return;
    float a = e1[(size_t)w * DIM + lane];
    float b = e2[(size_t)w * DIM + lane];
    float sa = waveSum(fabsf(a));
    float sb = waveSum(fabsf(b));
    float na = a / fmaxf(sa, 1e-12f);
    float nb2 = b / fmaxf(sb, 1e-12f);
    n1b[(size_t)w * DIM + lane] = (u16)f2bf(na);
    n2b[(size_t)w * DIM + lane] = (u16)f2bf(nb2);
    float p = waveSum(na * nb2);
    if (lane == 0) pos[w] = p;
}

#define SSL_JQ 8
// grid: (BATCH/64) * SSL_JQ blocks, 256 threads (4 waves; wave handles 16 i-rows)
__global__ __launch_bounds__(256) void k_ssl(const u16* __restrict__ n1b,
                                             const u16* __restrict__ n2b,
                                             float* __restrict__ ttl) {
    __shared__ u16 tile[128 * DIM];   // 16KB, XOR-swizzled
    int ib = blockIdx.x & 127;        // BATCH/64 = 128
    int jq = blockIdx.x >> 7;
    int wv = threadIdx.x >> 6, lane = threadIdx.x & 63;
    int i0 = ib * 64 + wv * 16;
    int r = lane & 15, g = lane >> 4;
    // A fragments: a0 covers k=0..31, a1 covers k=32..63
    s16x8 a0 = *(const s16x8*)&n1b[(size_t)(i0 + r) * DIM + g * 8];
    s16x8 a1 = *(const s16x8*)&n1b[(size_t)(i0 + r) * DIM + 32 + g * 8];
    f32x4 sume = {0.f, 0.f, 0.f, 0.f};
    int j0 = jq * (BATCH / SSL_JQ);
    for (int jt = 0; jt < BATCH / SSL_JQ; jt += 128) {
        __syncthreads();
        // stage 128 j-rows (1024 16B chunks), swizzle byte ^= ((row&7)<<4)
        for (int q = threadIdx.x; q < 1024; q += 256) {
            int row = q >> 3, ch = q & 7;
            uint4 src = *(const uint4*)&n2b[(size_t)(j0 + jt + row) * DIM + ch * 8];
            int dst = row * 128 + ((ch * 16) ^ ((row & 7) << 4));
            *(uint4*)((char*)tile + dst) = src;
        }
        __syncthreads();
#pragma unroll
        for (int tj = 0; tj < 8; ++tj) {
            int jr = tj * 16 + r;
            const char* base = (const char*)tile + jr * 128;
            int sw = (jr & 7) << 4;
            s16x8 b0 = *(const s16x8*)(base + ((g * 16) ^ sw));
            s16x8 b1 = *(const s16x8*)(base + (((4 + g) * 16) ^ sw));
            f32x4 d = {0.f, 0.f, 0.f, 0.f};
            d = __builtin_amdgcn_mfma_f32_16x16x32_bf16(a0, b0, d, 0, 0, 0);
            d = __builtin_amdgcn_mfma_f32_16x16x32_bf16(a1, b1, d, 0, 0, 0);
            sume.x += __expf(d.x * INV_T);
            sume.y += __expf(d.y * INV_T);
            sume.z += __expf(d.z * INV_T);
            sume.w += __expf(d.w * INV_T);
        }
    }
    // sum over cols: reduce across lane&15 (D layout: col=lane&15, row=(lane>>4)*4+reg)
#pragma unroll
    for (int m = 1; m < 16; m <<= 1) {
        sume.x += __shfl_xor(sume.x, m, 64);
        sume.y += __shfl_xor(sume.y, m, 64);
        sume.z += __shfl_xor(sume.z, m, 64);
        sume.w += __shfl_xor(sume.w, m, 64);
    }
    if (r == 0) {
        atomicAdd(&ttl[i0 + g * 4 + 0], sume.x);
        atomicAdd(&ttl[i0 + g * 4 + 1], sume.y);
        atomicAdd(&ttl[i0 + g * 4 + 2], sume.z);
        atomicAdd(&ttl[i0 + g * 4 + 3], sume.w);
    }
}

__global__ void k_sslfin(const float* __restrict__ ttl, const float* __restrict__ pos,
                         float* __restrict__ accums) {
    int i = blockIdx.x * blockDim.x + threadIdx.x;
    float v = logf(ttl[i]) - pos[i] * INV_T;
    v = waveSum(v);
    __shared__ float red[4];
    int lane = threadIdx.x & 63, w = threadIdx.x >> 6;
    if (lane == 0) red[w] = v;
    __syncthreads();
    if (threadIdx.x == 0) atomicAdd(&accums[0], red[0] + red[1] + red[2] + red[3]);
}

// ---------------- BPR: half-wave per triple, bf16 packed gathers ----------------
__global__ __launch_bounds__(256) void k_bpr(const uint32* __restrict__ accFbf,
                                             const uint32* __restrict__ ebf,
                                             const int* __restrict__ nl,
                                             const int* __restrict__ pl,
                                             const int* __restrict__ ngl,
                                             float* __restrict__ accums, int p) {
    int lane = threadIdx.x & 63;
    int half = lane >> 5, li = lane & 31;
    int wv = (blockIdx.x * blockDim.x + threadIdx.x) >> 6;
    int nw = (gridDim.x * blockDim.x) >> 6;
    float bprsum = 0.f, regsum = 0.f;
    for (int t0 = wv * 2 + half; t0 < p; t0 += nw * 2) {
        int a = nl[t0], b = pl[t0], c = ngl[t0];
        uint32 uu = accFbf[(size_t)a * 32 + li];
        uint32 vv = accFbf[(size_t)b * 32 + li];
        uint32 gg = accFbf[(size_t)c * 32 + li];
        uint32 u0 = ebf[(size_t)a * 32 + li];
        uint32 v0 = ebf[(size_t)b * 32 + li];
        uint32 g0 = ebf[(size_t)c * 32 + li];
        float pd = bfLo(uu) * bfLo(vv) + bfHi(uu) * bfHi(vv);
        float nd = bfLo(uu) * bfLo(gg) + bfHi(uu) * bfHi(gg);
        float rg = bfLo(u0) * bfLo(u0) + bfHi(u0) * bfHi(u0)
                 + bfLo(v0) * bfLo(v0) + bfHi(v0) * bfHi(v0)
                 + bfLo(g0) * bfLo(g0) + bfHi(g0) * bfHi(g0);
#pragma unroll
        for (int m = 1; m < 32; m <<= 1) {
            pd += __shfl_xor(pd, m, 64);
            nd += __shfl_xor(nd, m, 64);
            rg += __shfl_xor(rg, m, 64);
        }
        float x = (nd - pd) * (1.0f / 16.0f);   // fold (1/4)^2 layer-mean
        float sp = fmaxf(x, 0.f) + log1pf(__expf(-fabsf(x)));
        bprsum += sp;
        regsum += rg;
    }
    // lanes within a half hold identical sums; combine halves, lane 0 commits
    float bo = __shfl(bprsum, lane | 32, 64);
    float ro = __shfl(regsum, lane | 32, 64);
    if (lane == 0) {
        atomicAdd(&accums[1], bprsum + bo);
        atomicAdd(&accums[2], regsum + ro);
    }
}

__global__ void k_final(const float* __restrict__ accums, float* __restrict__ out) {
    if (threadIdx.x == 0 && blockIdx.x == 0) {
        float ssl = accums[0];
        float bpr = accums[1] * (1.0f / (float)NP);
        float reg = 0.5f * accums[2] * (1.0f / (float)BATCH);
        out[0] = ssl + bpr + LAM_REG * reg;
    }
}

// ---------------- launch ----------------
extern "C" void kernel_launch(void* const* d_in, const int* in_sizes, int n_in,
                              void* d_out, int out_size, void* d_ws, size_t ws_size,
                              hipStream_t stream) {
    (void)in_sizes; (void)n_in; (void)out_size; (void)ws_size;
    const float* emb   = (const float*)d_in[0];
    const float* vals1 = (const float*)d_in[1];
    const float* vals2 = (const float*)d_in[2];
    const float* vals0 = (const float*)d_in[3];
    const int* erow    = (const int*)d_in[4];
    const int* ecol    = (const int*)d_in[5];
    const int* nodes   = (const int*)d_in[6];
    const int* nl      = (const int*)d_in[7];
    const int* pl      = (const int*)d_in[8];
    const int* ngl     = (const int*)d_in[9];
    float* out = (float*)d_out;

    char* w = (char*)d_ws;
    size_t off = 0;
    auto alloc = [&](size_t bytes) -> void* {
        void* p = w + off;
        off = (off + bytes + 255) & ~(size_t)255;
        return p;
    };
    int*    counts = (int*)alloc((size_t)N_NODES * 4);
    int*    rowptr = (int*)alloc((size_t)(N_NODES + 1) * 4);
    int*    bsums  = (int*)alloc(512);
    int*    ccol   = (int*)alloc((size_t)N_EDGES * 4);      // aliased by accFbf later
    uint32* cw12   = (uint32*)alloc((size_t)N_EDGES * 4);   // (alias region cont'd)
    u16*    cw0    = (u16*)alloc((size_t)N_EDGES * 2);
    u16*    ebf    = (u16*)alloc((size_t)N_NODES * DIM * 2);
    u16*    A1     = (u16*)alloc((size_t)N_NODES * DIM * 2);
    u16*    A2     = (u16*)alloc((size_t)N_NODES * DIM * 2);
    u16*    A0     = (u16*)alloc((size_t)N_NODES * DIM * 2);
    u16*    B1     = (u16*)alloc((size_t)N_NODES * DIM * 2);
    u16*    B2     = (u16*)alloc((size_t)N_NODES * DIM * 2);
    u16*    B0     = (u16*)alloc((size_t)N_NODES * DIM * 2);
    float*  accF   = (float*)alloc((size_t)N_NODES * DIM * 4);
    float*  accB1  = (float*)alloc((size_t)BATCH * DIM * 4);
    float*  accB2  = (float*)alloc((size_t)BATCH * DIM * 4);
    u16*    n1b    = (u16*)alloc((size_t)BATCH * DIM * 2);
    u16*    n2b    = (u16*)alloc((size_t)BATCH * DIM * 2);
    float*  pos    = (float*)alloc((size_t)BATCH * 4);
    float*  ttl    = (float*)alloc((size_t)BATCH * 4);
    float*  accums = (float*)alloc(256);
    // accFbf reuses the (dead-after-pass3) ccol+cw12 region: 12.8MB needed, 12.8MB there
    uint32* accFbf = (uint32*)ccol;

    hipMemsetAsync(counts, 0, (size_t)N_NODES * 4, stream);
    hipMemsetAsync(ttl, 0, (size_t)BATCH * 4, stream);
    hipMemsetAsync(accums, 0, 256, stream);

    // CSR build
    k_hist<<<N_EDGES / 256, 256, 0, stream>>>(erow, counts, N_EDGES);
    k_scan1<<<NB_SCAN, SCAN_CHUNK, 0, stream>>>(counts, rowptr, bsums, N_NODES);
    k_scan2<<<1, 128, 0, stream>>>(bsums, NB_SCAN, rowptr, N_NODES, N_EDGES);
    k_scan3<<<NB_SCAN, SCAN_CHUNK, 0, stream>>>(rowptr, bsums, N_NODES);
    hipMemsetAsync(counts, 0, (size_t)N_NODES * 4, stream);
    k_scatter<<<N_EDGES / 256, 256, 0, stream>>>(erow, ecol, vals1, vals2, vals0,
                                                 rowptr, counts, ccol, cw12, cw0,
                                                 N_EDGES);
    k_cvtbf<<<(N_NODES * 32 + 255) / 256, 256, 0, stream>>>(emb, (uint32*)ebf,
                                                            N_NODES * 32);

    const int propGrid = (N_NODES * 64 + 255) / 256;   // wave per node
    const int gGrid = BATCH / 4;

    // layer 1 (all three views fused; emb gathered once)
    k_prop_l1<<<propGrid, 256, 0, stream>>>(rowptr, ccol, cw12, cw0, ebf, emb,
                                            A1, A2, A0, accF, N_NODES);
    k_gatherB<<<gGrid, 256, 0, stream>>>(nodes, A1, A2, accB1, accB2, emb, 1);
    // layer 2
    k_prop_l23<<<propGrid, 256, 0, stream>>>(rowptr, ccol, cw12, cw0, A1, A2, A0,
                                             B1, B2, B0, accF, N_NODES);
    k_gatherB<<<gGrid, 256, 0, stream>>>(nodes, B1, B2, accB1, accB2, emb, 0);
    // layer 3 (outputs reuse A buffers — A already consumed)
    k_prop_l23<<<propGrid, 256, 0, stream>>>(rowptr, ccol, cw12, cw0, B1, B2, B0,
                                             A1, A2, A0, accF, N_NODES);
    k_gatherB<<<gGrid, 256, 0, stream>>>(nodes, A1, A2, accB1, accB2, emb, 0);

    // accF -> bf16 for BPR (into dead CSR memory)
    k_cvtbf<<<(N_NODES * 32 + 255) / 256, 256, 0, stream>>>(accF, accFbf, N_NODES * 32);

    // SSL
    k_norm<<<gGrid, 256, 0, stream>>>(accB1, accB2, n1b, n2b, pos, BATCH);
    k_ssl<<<(BATCH / 64) * SSL_JQ, 256, 0, stream>>>(n1b, n2b, ttl);
    k_sslfin<<<BATCH / 256, 256, 0, stream>>>(ttl, pos, accums);

    // BPR + reg
    k_bpr<<<2048, 256, 0, stream>>>(accFbf, (const uint32*)ebf, nl, pl, ngl, accums, NP);

    k_final<<<1, 64, 0, stream>>>(accums, out);
}

// Round 3
// 690.002 us; speedup vs baseline: 2.3493x; 1.1382x over previous
//
#include <hip/hip_runtime.h>
#include <cstdint>
#include <cstddef>

#define N_NODES 100000
#define DIM     64
#define N_EDGES 1600000
#define N_EPAD  2000000   // capacity for per-row pad-to-4
#define BATCH   8192
#define NP      262144
#define INV_T   2.0f      // 1/T, T=0.5
#define LAM_REG 1e-4f

#define SCAN_CHUNK 1024
#define NB_SCAN ((N_NODES + SCAN_CHUNK - 1) / SCAN_CHUNK)   // 98

typedef unsigned int   uint32;
typedef unsigned short u16;
typedef __attribute__((ext_vector_type(4))) float f32x4;
typedef __attribute__((ext_vector_type(8))) short s16x8;

static __device__ __forceinline__ uint32 f2bf(float x) {
    uint32 b = __float_as_uint(x);
    return (b + 0x7fffu + ((b >> 16) & 1u)) >> 16;   // rne, low 16 bits
}
static __device__ __forceinline__ float bfLo(uint32 u) { return __uint_as_float(u << 16); }
static __device__ __forceinline__ float bfHi(uint32 u) { return __uint_as_float(u & 0xffff0000u); }

static __device__ __forceinline__ float waveSum(float v) {
#pragma unroll
    for (int off = 32; off > 0; off >>= 1) v += __shfl_xor(v, off, 64);
    return v;
}

// ---------------- CSR build (rows padded to multiple of 4) ----------------
__global__ void k_hist(const int* __restrict__ erow, int* __restrict__ counts, int e) {
    int i = blockIdx.x * blockDim.x + threadIdx.x;
    if (i < e) atomicAdd(&counts[erow[i]], 1);
}

__global__ void k_scan1(const int* __restrict__ counts, int* __restrict__ rowptr,
                        int* __restrict__ bsums, int n) {
    __shared__ int tmp[SCAN_CHUNK];
    int gid = blockIdx.x * SCAN_CHUNK + threadIdx.x;
    int v = (gid < n) ? ((counts[gid] + 3) & ~3) : 0;   // padded count
    tmp[threadIdx.x] = v;
    __syncthreads();
    for (int off = 1; off < SCAN_CHUNK; off <<= 1) {
        int t = (threadIdx.x >= off) ? tmp[threadIdx.x - off] : 0;
        __syncthreads();
        tmp[threadIdx.x] += t;
        __syncthreads();
    }
    if (gid < n) rowptr[gid] = tmp[threadIdx.x] - v;   // exclusive
    if (threadIdx.x == SCAN_CHUNK - 1) bsums[blockIdx.x] = tmp[threadIdx.x];
}

__global__ void k_scan2(int* __restrict__ bsums, int nb, int* __restrict__ rowptr, int n) {
    __shared__ int tmp[128];
    int v = (threadIdx.x < nb) ? bsums[threadIdx.x] : 0;
    tmp[threadIdx.x] = v;
    __syncthreads();
    for (int off = 1; off < 128; off <<= 1) {
        int t = (threadIdx.x >= off) ? tmp[threadIdx.x - off] : 0;
        __syncthreads();
        tmp[threadIdx.x] += t;
        __syncthreads();
    }
    if (threadIdx.x < nb) bsums[threadIdx.x] = tmp[threadIdx.x] - v;   // exclusive
    if (threadIdx.x == nb - 1) rowptr[n] = tmp[threadIdx.x] + bsums[threadIdx.x] - 0
        , rowptr[n] = tmp[threadIdx.x];   // inclusive total (padded)
}

__global__ void k_scan3(int* __restrict__ rowptr, const int* __restrict__ bsums, int n) {
    int gid = blockIdx.x * SCAN_CHUNK + threadIdx.x;
    if (gid < n) rowptr[gid] += bsums[blockIdx.x];
}

__global__ void k_scatter(const int* __restrict__ erow, const int* __restrict__ ecol,
                          const float* __restrict__ v1, const float* __restrict__ v2,
                          const float* __restrict__ v0,
                          const int* __restrict__ rowptr, int* __restrict__ cursor,
                          int* __restrict__ ccol, uint32* __restrict__ cw12,
                          u16* __restrict__ cw0, int e) {
    int i = blockIdx.x * blockDim.x + threadIdx.x;
    if (i >= e) return;
    int r = erow[i];
    int p = rowptr[r] + atomicAdd(&cursor[r], 1);
    ccol[p] = ecol[i];
    cw12[p] = f2bf(v1[i]) | (f2bf(v2[i]) << 16);
    cw0[p] = (u16)f2bf(v0[i]);
}

// emb fp32 -> bf16 table + per-node squared norm (wave per node)
__global__ void k_cvtsq(const float* __restrict__ emb, u16* __restrict__ ebf,
                        float* __restrict__ sqn) {
    int t = blockIdx.x * blockDim.x + threadIdx.x;
    int node = t >> 6, lane = t & 63;
    float x = emb[(size_t)node * DIM + lane];
    ebf[(size_t)node * DIM + lane] = (u16)f2bf(x);
    float s = waveSum(x * x);
    if (lane == 0) sqn[node] = s;
}

// ---------------- propagation: wave per node, lane = dim ----------------
// metadata via wave-uniform (readfirstlane-rooted) loads; rows padded to 4
__global__ __launch_bounds__(256) void k_prop_l1(
    const int* __restrict__ rowptr, const int* __restrict__ ccol,
    const uint32* __restrict__ cw12, const u16* __restrict__ cw0,
    const u16* __restrict__ ebf,
    u16* __restrict__ o1, u16* __restrict__ o2, u16* __restrict__ o0,
    u16* __restrict__ accFbf) {
    int t = blockIdx.x * blockDim.x + threadIdx.x;
    int node = __builtin_amdgcn_readfirstlane(t >> 6);
    int lane = t & 63;
    int s = rowptr[node], e = rowptr[node + 1];
    float a1 = 0.f, a2 = 0.f, a0 = 0.f;
    for (int k = s; k < e; k += 4) {
        int4  c  = *(const int4*)(ccol + k);
        uint4 w  = *(const uint4*)(cw12 + k);
        uint2 wp = *(const uint2*)(cw0 + k);
        float x0 = bfLo((uint32)ebf[(size_t)c.x * DIM + lane]);
        float x1 = bfLo((uint32)ebf[(size_t)c.y * DIM + lane]);
        float x2 = bfLo((uint32)ebf[(size_t)c.z * DIM + lane]);
        float x3 = bfLo((uint32)ebf[(size_t)c.w * DIM + lane]);
        a1 += bfLo(w.x) * x0 + bfLo(w.y) * x1 + bfLo(w.z) * x2 + bfLo(w.w) * x3;
        a2 += bfHi(w.x) * x0 + bfHi(w.y) * x1 + bfHi(w.z) * x2 + bfHi(w.w) * x3;
        a0 += bfLo(wp.x) * x0 + bfHi(wp.x) * x1 + bfLo(wp.y) * x2 + bfHi(wp.y) * x3;
    }
    size_t off = (size_t)node * DIM + lane;
    o1[off] = (u16)f2bf(a1);
    o2[off] = (u16)f2bf(a2);
    o0[off] = (u16)f2bf(a0);
    accFbf[off] = (u16)f2bf(bfLo((uint32)ebf[off]) + a0);
}

__global__ __launch_bounds__(256) void k_prop_l23(
    const int* __restrict__ rowptr, const int* __restrict__ ccol,
    const uint32* __restrict__ cw12, const u16* __restrict__ cw0,
    const u16* __restrict__ t1, const u16* __restrict__ t2, const u16* __restrict__ t0,
    u16* __restrict__ o1, u16* __restrict__ o2, u16* __restrict__ o0,
    u16* __restrict__ accFbf) {
    int t = blockIdx.x * blockDim.x + threadIdx.x;
    int node = __builtin_amdgcn_readfirstlane(t >> 6);
    int lane = t & 63;
    int s = rowptr[node], e = rowptr[node + 1];
    float a1 = 0.f, a2 = 0.f, a0 = 0.f;
    for (int k = s; k < e; k += 4) {
        int4  c  = *(const int4*)(ccol + k);
        uint4 w  = *(const uint4*)(cw12 + k);
        uint2 wp = *(const uint2*)(cw0 + k);
        size_t r0 = (size_t)c.x * DIM + lane, r1 = (size_t)c.y * DIM + lane;
        size_t r2 = (size_t)c.z * DIM + lane, r3 = (size_t)c.w * DIM + lane;
        float p0 = bfLo((uint32)t1[r0]), p1 = bfLo((uint32)t1[r1]);
        float p2 = bfLo((uint32)t1[r2]), p3 = bfLo((uint32)t1[r3]);
        float q0 = bfLo((uint32)t2[r0]), q1 = bfLo((uint32)t2[r1]);
        float q2 = bfLo((uint32)t2[r2]), q3 = bfLo((uint32)t2[r3]);
        float z0 = bfLo((uint32)t0[r0]), z1 = bfLo((uint32)t0[r1]);
        float z2 = bfLo((uint32)t0[r2]), z3 = bfLo((uint32)t0[r3]);
        a1 += bfLo(w.x) * p0 + bfLo(w.y) * p1 + bfLo(w.z) * p2 + bfLo(w.w) * p3;
        a2 += bfHi(w.x) * q0 + bfHi(w.y) * q1 + bfHi(w.z) * q2 + bfHi(w.w) * q3;
        a0 += bfLo(wp.x) * z0 + bfHi(wp.x) * z1 + bfLo(wp.y) * z2 + bfHi(wp.y) * z3;
    }
    size_t off = (size_t)node * DIM + lane;
    o1[off] = (u16)f2bf(a1);
    o2[off] = (u16)f2bf(a2);
    o0[off] = (u16)f2bf(a0);
    accFbf[off] = (u16)f2bf(bfLo((uint32)accFbf[off]) + a0);
}

// gather batch rows of both views (wave per row)
__global__ void k_gatherB(const int* __restrict__ nodes, const u16* __restrict__ t1,
                          const u16* __restrict__ t2, const u16* __restrict__ ebf,
                          float* __restrict__ accB1, float* __restrict__ accB2,
                          int init) {
    int t = blockIdx.x * blockDim.x + threadIdx.x;
    int b = t >> 6, lane = t & 63;
    int nd = nodes[b];
    size_t src = (size_t)nd * DIM + lane;
    size_t off = (size_t)b * DIM + lane;
    float x1 = bfLo((uint32)t1[src]);
    float x2 = bfLo((uint32)t2[src]);
    if (init) {
        float em = bfLo((uint32)ebf[src]);
        accB1[off] = em + x1;
        accB2[off] = em + x2;
    } else {
        accB1[off] += x1;
        accB2[off] += x2;
    }
}

// final gather + l1 normalize + pos score (wave per row)
__global__ void k_gnorm(const int* __restrict__ nodes, const u16* __restrict__ t1,
                        const u16* __restrict__ t2, const float* __restrict__ accB1,
                        const float* __restrict__ accB2, u16* __restrict__ n1b,
                        u16* __restrict__ n2b, float* __restrict__ pos) {
    int t = blockIdx.x * blockDim.x + threadIdx.x;
    int b = t >> 6, lane = t & 63;
    int nd = nodes[b];
    size_t src = (size_t)nd * DIM + lane;
    size_t off = (size_t)b * DIM + lane;
    float a = accB1[off] + bfLo((uint32)t1[src]);
    float c = accB2[off] + bfLo((uint32)t2[src]);
    float sa = waveSum(fabsf(a));
    float sc = waveSum(fabsf(c));
    float na = a / fmaxf(sa, 1e-12f);
    float nc = c / fmaxf(sc, 1e-12f);
    n1b[off] = (u16)f2bf(na);
    n2b[off] = (u16)f2bf(nc);
    float p = waveSum(na * nc);
    if (lane == 0) pos[b] = p;
}

// ---------------- SSL (MFMA) ----------------
#define SSL_JQ 8
__global__ __launch_bounds__(256) void k_ssl(const u16* __restrict__ n1b,
                                             const u16* __restrict__ n2b,
                                             float* __restrict__ ttl) {
    __shared__ u16 tile[128 * DIM];   // 16KB, XOR-swizzled
    int ib = blockIdx.x & 127;
    int jq = blockIdx.x >> 7;
    int wv = threadIdx.x >> 6, lane = threadIdx.x & 63;
    int i0 = ib * 64 + wv * 16;
    int r = lane & 15, g = lane >> 4;
    s16x8 a0 = *(const s16x8*)&n1b[(size_t)(i0 + r) * DIM + g * 8];
    s16x8 a1 = *(const s16x8*)&n1b[(size_t)(i0 + r) * DIM + 32 + g * 8];
    f32x4 sume = {0.f, 0.f, 0.f, 0.f};
    int j0 = jq * (BATCH / SSL_JQ);
    for (int jt = 0; jt < BATCH / SSL_JQ; jt += 128) {
        __syncthreads();
        for (int q = threadIdx.x; q < 1024; q += 256) {
            int row = q >> 3, ch = q & 7;
            uint4 src = *(const uint4*)&n2b[(size_t)(j0 + jt + row) * DIM + ch * 8];
            int dst = row * 128 + ((ch * 16) ^ ((row & 7) << 4));
            *(uint4*)((char*)tile + dst) = src;
        }
        __syncthreads();
#pragma unroll
        for (int tj = 0; tj < 8; ++tj) {
            int jr = tj * 16 + r;
            const char* base = (const char*)tile + jr * 128;
            int sw = (jr & 7) << 4;
            s16x8 b0 = *(const s16x8*)(base + ((g * 16) ^ sw));
            s16x8 b1 = *(const s16x8*)(base + (((4 + g) * 16) ^ sw));
            f32x4 d = {0.f, 0.f, 0.f, 0.f};
            d = __builtin_amdgcn_mfma_f32_16x16x32_bf16(a0, b0, d, 0, 0, 0);
            d = __builtin_amdgcn_mfma_f32_16x16x32_bf16(a1, b1, d, 0, 0, 0);
            sume.x += __expf(d.x * INV_T);
            sume.y += __expf(d.y * INV_T);
            sume.z += __expf(d.z * INV_T);
            sume.w += __expf(d.w * INV_T);
        }
    }
#pragma unroll
    for (int m = 1; m < 16; m <<= 1) {
        sume.x += __shfl_xor(sume.x, m, 64);
        sume.y += __shfl_xor(sume.y, m, 64);
        sume.z += __shfl_xor(sume.z, m, 64);
        sume.w += __shfl_xor(sume.w, m, 64);
    }
    if (r == 0) {
        atomicAdd(&ttl[i0 + g * 4 + 0], sume.x);
        atomicAdd(&ttl[i0 + g * 4 + 1], sume.y);
        atomicAdd(&ttl[i0 + g * 4 + 2], sume.z);
        atomicAdd(&ttl[i0 + g * 4 + 3], sume.w);
    }
}

__global__ void k_sslfin(const float* __restrict__ ttl, const float* __restrict__ pos,
                         float* __restrict__ accums) {
    int i = blockIdx.x * blockDim.x + threadIdx.x;
    float v = logf(ttl[i]) - pos[i] * INV_T;
    v = waveSum(v);
    __shared__ float red[4];
    int lane = threadIdx.x & 63, w = threadIdx.x >> 6;
    if (lane == 0) red[w] = v;
    __syncthreads();
    if (threadIdx.x == 0) atomicAdd(&accums[0], red[0] + red[1] + red[2] + red[3]);
}

// ---------------- BPR: quarter-wave per triple, sqnorm for reg ----------------
__global__ __launch_bounds__(256) void k_bpr(const uint32* __restrict__ accFbf,
                                             const float* __restrict__ sqn,
                                             const int* __restrict__ nl,
                                             const int* __restrict__ pl,
                                             const int* __restrict__ ngl,
                                             float* __restrict__ accums, int p) {
    int lane = threadIdx.x & 63;
    int q = lane >> 4, li = lane & 15;
    int wv = (blockIdx.x * blockDim.x + threadIdx.x) >> 6;
    int nw = (gridDim.x * blockDim.x) >> 6;
    const uint2* tab = (const uint2*)accFbf;
    float bprsum = 0.f, regsum = 0.f;
    for (int t0 = wv * 4 + q; t0 < p; t0 += nw * 4) {
        int a = nl[t0], b = pl[t0], c = ngl[t0];
        uint2 uu = tab[(size_t)a * 16 + li];
        uint2 vv = tab[(size_t)b * 16 + li];
        uint2 gg = tab[(size_t)c * 16 + li];
        float pd = bfLo(uu.x) * bfLo(vv.x) + bfHi(uu.x) * bfHi(vv.x)
                 + bfLo(uu.y) * bfLo(vv.y) + bfHi(uu.y) * bfHi(vv.y);
        float nd = bfLo(uu.x) * bfLo(gg.x) + bfHi(uu.x) * bfHi(gg.x)
                 + bfLo(uu.y) * bfLo(gg.y) + bfHi(uu.y) * bfHi(gg.y);
#pragma unroll
        for (int m = 1; m < 16; m <<= 1) {
            pd += __shfl_xor(pd, m, 64);
            nd += __shfl_xor(nd, m, 64);
        }
        float x = (nd - pd) * (1.0f / 16.0f);   // fold (1/4)^2 layer-mean
        float sp = fmaxf(x, 0.f) + log1pf(__expf(-fabsf(x)));
        float rg = sqn[a] + sqn[b] + sqn[c];
        bprsum += (li == 0) ? sp : 0.f;
        regsum += (li == 0) ? rg : 0.f;
    }
    bprsum = waveSum(bprsum);
    regsum = waveSum(regsum);
    if (lane == 0) {
        atomicAdd(&accums[1], bprsum);
        atomicAdd(&accums[2], regsum);
    }
}

__global__ void k_final(const float* __restrict__ accums, float* __restrict__ out) {
    if (threadIdx.x == 0 && blockIdx.x == 0) {
        float ssl = accums[0];
        float bpr = accums[1] * (1.0f / (float)NP);
        float reg = 0.5f * accums[2] * (1.0f / (float)BATCH);
        out[0] = ssl + bpr + LAM_REG * reg;
    }
}

// ---------------- launch ----------------
extern "C" void kernel_launch(void* const* d_in, const int* in_sizes, int n_in,
                              void* d_out, int out_size, void* d_ws, size_t ws_size,
                              hipStream_t stream) {
    (void)in_sizes; (void)n_in; (void)out_size; (void)ws_size;
    const float* emb   = (const float*)d_in[0];
    const float* vals1 = (const float*)d_in[1];
    const float* vals2 = (const float*)d_in[2];
    const float* vals0 = (const float*)d_in[3];
    const int* erow    = (const int*)d_in[4];
    const int* ecol    = (const int*)d_in[5];
    const int* nodes   = (const int*)d_in[6];
    const int* nl      = (const int*)d_in[7];
    const int* pl      = (const int*)d_in[8];
    const int* ngl     = (const int*)d_in[9];
    float* out = (float*)d_out;

    char* w = (char*)d_ws;
    size_t off = 0;
    auto alloc = [&](size_t bytes) -> void* {
        void* p = w + off;
        off = (off + bytes + 255) & ~(size_t)255;
        return p;
    };
    int*    counts = (int*)alloc((size_t)N_NODES * 4);
    int*    rowptr = (int*)alloc((size_t)(N_NODES + 1) * 4);
    int*    bsums  = (int*)alloc(512);
    int*    ccol   = (int*)alloc((size_t)N_EPAD * 4);
    uint32* cw12   = (uint32*)alloc((size_t)N_EPAD * 4);
    u16*    cw0    = (u16*)alloc((size_t)N_EPAD * 2);
    u16*    ebf    = (u16*)alloc((size_t)N_NODES * DIM * 2);
    float*  sqn    = (float*)alloc((size_t)N_NODES * 4);
    u16*    A1     = (u16*)alloc((size_t)N_NODES * DIM * 2);
    u16*    A2     = (u16*)alloc((size_t)N_NODES * DIM * 2);
    u16*    A0     = (u16*)alloc((size_t)N_NODES * DIM * 2);
    u16*    B1     = (u16*)alloc((size_t)N_NODES * DIM * 2);
    u16*    B2     = (u16*)alloc((size_t)N_NODES * DIM * 2);
    u16*    B0     = (u16*)alloc((size_t)N_NODES * DIM * 2);
    u16*    accFbf = (u16*)alloc((size_t)N_NODES * DIM * 2);
    float*  accB1  = (float*)alloc((size_t)BATCH * DIM * 4);
    float*  accB2  = (float*)alloc((size_t)BATCH * DIM * 4);
    u16*    n1b    = (u16*)alloc((size_t)BATCH * DIM * 2);
    u16*    n2b    = (u16*)alloc((size_t)BATCH * DIM * 2);
    float*  pos    = (float*)alloc((size_t)BATCH * 4);
    float*  ttl    = (float*)alloc((size_t)BATCH * 4);
    float*  accums = (float*)alloc(256);

    hipMemsetAsync(counts, 0, (size_t)N_NODES * 4, stream);
    hipMemsetAsync(ttl, 0, (size_t)BATCH * 4, stream);
    hipMemsetAsync(accums, 0, 256, stream);
    // zero edge arrays so pad slots contribute w=0 edges at col 0
    hipMemsetAsync(ccol, 0, (size_t)N_EPAD * 4, stream);
    hipMemsetAsync(cw12, 0, (size_t)N_EPAD * 4, stream);
    hipMemsetAsync(cw0, 0, (size_t)N_EPAD * 2, stream);

    // CSR build (padded)
    k_hist<<<N_EDGES / 256, 256, 0, stream>>>(erow, counts, N_EDGES);
    k_scan1<<<NB_SCAN, SCAN_CHUNK, 0, stream>>>(counts, rowptr, bsums, N_NODES);
    k_scan2<<<1, 128, 0, stream>>>(bsums, NB_SCAN, rowptr, N_NODES);
    k_scan3<<<NB_SCAN, SCAN_CHUNK, 0, stream>>>(rowptr, bsums, N_NODES);
    hipMemsetAsync(counts, 0, (size_t)N_NODES * 4, stream);
    k_scatter<<<N_EDGES / 256, 256, 0, stream>>>(erow, ecol, vals1, vals2, vals0,
                                                 rowptr, counts, ccol, cw12, cw0,
                                                 N_EDGES);
    k_cvtsq<<<N_NODES / 4, 256, 0, stream>>>(emb, ebf, sqn);

    const int propGrid = N_NODES / 4;   // wave per node, 4 waves/block
    const int gGrid = BATCH / 4;

    k_prop_l1<<<propGrid, 256, 0, stream>>>(rowptr, ccol, cw12, cw0, ebf,
                                            A1, A2, A0, accFbf);
    k_gatherB<<<gGrid, 256, 0, stream>>>(nodes, A1, A2, ebf, accB1, accB2, 1);
    k_prop_l23<<<propGrid, 256, 0, stream>>>(rowptr, ccol, cw12, cw0, A1, A2, A0,
                                             B1, B2, B0, accFbf);
    k_gatherB<<<gGrid, 256, 0, stream>>>(nodes, B1, B2, ebf, accB1, accB2, 0);
    k_prop_l23<<<propGrid, 256, 0, stream>>>(rowptr, ccol, cw12, cw0, B1, B2, B0,
                                             A1, A2, A0, accFbf);
    k_gnorm<<<gGrid, 256, 0, stream>>>(nodes, A1, A2, accB1, accB2, n1b, n2b, pos);

    // SSL
    k_ssl<<<(BATCH / 64) * SSL_JQ, 256, 0, stream>>>(n1b, n2b, ttl);
    k_sslfin<<<BATCH / 256, 256, 0, stream>>>(ttl, pos, accums);

    // BPR + reg
    k_bpr<<<2048, 256, 0, stream>>>((const uint32*)accFbf, sqn, nl, pl, ngl, accums, NP);

    k_final<<<1, 64, 0, stream>>>(accums, out);
}

// Round 4
// 492.609 us; speedup vs baseline: 3.2906x; 1.4007x over previous
//
#include <hip/hip_runtime.h>
#include <cstdint>
#include <cstddef>

#define N_NODES 100000
#define DIM     64
#define N_EDGES 1600000
#define N_EPAD  2000000   // capacity for per-row pad-to-4
#define BATCH   8192
#define NP      262144
#define INV_T   2.0f      // 1/T, T=0.5
#define LAM_REG 1e-4f

#define SCAN_CHUNK 1024
#define NB_SCAN ((N_NODES + SCAN_CHUNK - 1) / SCAN_CHUNK)   // 98

#define BPR_BLOCKS 2048

typedef unsigned int   uint32;
typedef unsigned short u16;
typedef __attribute__((ext_vector_type(4))) float f32x4;
typedef __attribute__((ext_vector_type(8))) short s16x8;

static __device__ __forceinline__ uint32 f2bf(float x) {
    uint32 b = __float_as_uint(x);
    return (b + 0x7fffu + ((b >> 16) & 1u)) >> 16;   // rne, low 16 bits
}
static __device__ __forceinline__ float bfLo(uint32 u) { return __uint_as_float(u << 16); }
static __device__ __forceinline__ float bfHi(uint32 u) { return __uint_as_float(u & 0xffff0000u); }

static __device__ __forceinline__ float waveSum(float v) {
#pragma unroll
    for (int off = 32; off > 0; off >>= 1) v += __shfl_xor(v, off, 64);
    return v;
}

// ---------------- CSR build (rows padded to multiple of 4) ----------------
__global__ void k_hist(const int* __restrict__ erow, int* __restrict__ counts, int e) {
    int i = blockIdx.x * blockDim.x + threadIdx.x;
    if (i < e) atomicAdd(&counts[erow[i]], 1);
}

__global__ void k_scan1(const int* __restrict__ counts, int* __restrict__ rowptr,
                        int* __restrict__ bsums, int n) {
    __shared__ int tmp[SCAN_CHUNK];
    int gid = blockIdx.x * SCAN_CHUNK + threadIdx.x;
    int v = (gid < n) ? ((counts[gid] + 3) & ~3) : 0;   // padded count
    tmp[threadIdx.x] = v;
    __syncthreads();
    for (int off = 1; off < SCAN_CHUNK; off <<= 1) {
        int t = (threadIdx.x >= off) ? tmp[threadIdx.x - off] : 0;
        __syncthreads();
        tmp[threadIdx.x] += t;
        __syncthreads();
    }
    if (gid < n) rowptr[gid] = tmp[threadIdx.x] - v;   // exclusive
    if (threadIdx.x == SCAN_CHUNK - 1) bsums[blockIdx.x] = tmp[threadIdx.x];
}

__global__ void k_scan2(int* __restrict__ bsums, int nb, int* __restrict__ rowptr, int n) {
    __shared__ int tmp[128];
    int v = (threadIdx.x < nb) ? bsums[threadIdx.x] : 0;
    tmp[threadIdx.x] = v;
    __syncthreads();
    for (int off = 1; off < 128; off <<= 1) {
        int t = (threadIdx.x >= off) ? tmp[threadIdx.x - off] : 0;
        __syncthreads();
        tmp[threadIdx.x] += t;
        __syncthreads();
    }
    if (threadIdx.x < nb) bsums[threadIdx.x] = tmp[threadIdx.x] - v;   // exclusive
    if (threadIdx.x == nb - 1) rowptr[n] = tmp[threadIdx.x];           // padded total
}

__global__ void k_scan3(int* __restrict__ rowptr, const int* __restrict__ bsums, int n) {
    int gid = blockIdx.x * SCAN_CHUNK + threadIdx.x;
    if (gid < n) rowptr[gid] += bsums[blockIdx.x];
}

__global__ void k_scatter(const int* __restrict__ erow, const int* __restrict__ ecol,
                          const float* __restrict__ v1, const float* __restrict__ v2,
                          const float* __restrict__ v0,
                          const int* __restrict__ rowptr, int* __restrict__ cursor,
                          int* __restrict__ ccol, uint32* __restrict__ cw12,
                          u16* __restrict__ cw0, int e) {
    int i = blockIdx.x * blockDim.x + threadIdx.x;
    if (i >= e) return;
    int r = erow[i];
    int p = rowptr[r] + atomicAdd(&cursor[r], 1);
    ccol[p] = ecol[i];
    cw12[p] = f2bf(v1[i]) | (f2bf(v2[i]) << 16);
    cw0[p] = (u16)f2bf(v0[i]);
}

// emb fp32 -> bf16 table + per-node squared norm (wave per node)
__global__ void k_cvtsq(const float* __restrict__ emb, u16* __restrict__ ebf,
                        float* __restrict__ sqn) {
    int t = blockIdx.x * blockDim.x + threadIdx.x;
    int node = t >> 6, lane = t & 63;
    float x = emb[(size_t)node * DIM + lane];
    ebf[(size_t)node * DIM + lane] = (u16)f2bf(x);
    float s = waveSum(x * x);
    if (lane == 0) sqn[node] = s;
}

// ---------------- propagation: wave per node, lane = dim ----------------
__global__ __launch_bounds__(256) void k_prop_l1(
    const int* __restrict__ rowptr, const int* __restrict__ ccol,
    const uint32* __restrict__ cw12, const u16* __restrict__ cw0,
    const u16* __restrict__ ebf,
    u16* __restrict__ o1, u16* __restrict__ o2, u16* __restrict__ o0,
    u16* __restrict__ accFbf) {
    int t = blockIdx.x * blockDim.x + threadIdx.x;
    int node = __builtin_amdgcn_readfirstlane(t >> 6);
    int lane = t & 63;
    int s = rowptr[node], e = rowptr[node + 1];
    float a1 = 0.f, a2 = 0.f, a0 = 0.f;
    for (int k = s; k < e; k += 4) {
        int4  c  = *(const int4*)(ccol + k);
        uint4 w  = *(const uint4*)(cw12 + k);
        uint2 wp = *(const uint2*)(cw0 + k);
        float x0 = bfLo((uint32)ebf[(size_t)c.x * DIM + lane]);
        float x1 = bfLo((uint32)ebf[(size_t)c.y * DIM + lane]);
        float x2 = bfLo((uint32)ebf[(size_t)c.z * DIM + lane]);
        float x3 = bfLo((uint32)ebf[(size_t)c.w * DIM + lane]);
        a1 += bfLo(w.x) * x0 + bfLo(w.y) * x1 + bfLo(w.z) * x2 + bfLo(w.w) * x3;
        a2 += bfHi(w.x) * x0 + bfHi(w.y) * x1 + bfHi(w.z) * x2 + bfHi(w.w) * x3;
        a0 += bfLo(wp.x) * x0 + bfHi(wp.x) * x1 + bfLo(wp.y) * x2 + bfHi(wp.y) * x3;
    }
    size_t off = (size_t)node * DIM + lane;
    o1[off] = (u16)f2bf(a1);
    o2[off] = (u16)f2bf(a2);
    o0[off] = (u16)f2bf(a0);
    accFbf[off] = (u16)f2bf(bfLo((uint32)ebf[off]) + a0);
}

__global__ __launch_bounds__(256) void k_prop_l23(
    const int* __restrict__ rowptr, const int* __restrict__ ccol,
    const uint32* __restrict__ cw12, const u16* __restrict__ cw0,
    const u16* __restrict__ t1, const u16* __restrict__ t2, const u16* __restrict__ t0,
    u16* __restrict__ o1, u16* __restrict__ o2, u16* __restrict__ o0,
    u16* __restrict__ accFbf) {
    int t = blockIdx.x * blockDim.x + threadIdx.x;
    int node = __builtin_amdgcn_readfirstlane(t >> 6);
    int lane = t & 63;
    int s = rowptr[node], e = rowptr[node + 1];
    float a1 = 0.f, a2 = 0.f, a0 = 0.f;
    for (int k = s; k < e; k += 4) {
        int4  c  = *(const int4*)(ccol + k);
        uint4 w  = *(const uint4*)(cw12 + k);
        uint2 wp = *(const uint2*)(cw0 + k);
        size_t r0 = (size_t)c.x * DIM + lane, r1 = (size_t)c.y * DIM + lane;
        size_t r2 = (size_t)c.z * DIM + lane, r3 = (size_t)c.w * DIM + lane;
        float p0 = bfLo((uint32)t1[r0]), p1 = bfLo((uint32)t1[r1]);
        float p2 = bfLo((uint32)t1[r2]), p3 = bfLo((uint32)t1[r3]);
        float q0 = bfLo((uint32)t2[r0]), q1 = bfLo((uint32)t2[r1]);
        float q2 = bfLo((uint32)t2[r2]), q3 = bfLo((uint32)t2[r3]);
        float z0 = bfLo((uint32)t0[r0]), z1 = bfLo((uint32)t0[r1]);
        float z2 = bfLo((uint32)t0[r2]), z3 = bfLo((uint32)t0[r3]);
        a1 += bfLo(w.x) * p0 + bfLo(w.y) * p1 + bfLo(w.z) * p2 + bfLo(w.w) * p3;
        a2 += bfHi(w.x) * q0 + bfHi(w.y) * q1 + bfHi(w.z) * q2 + bfHi(w.w) * q3;
        a0 += bfLo(wp.x) * z0 + bfHi(wp.x) * z1 + bfLo(wp.y) * z2 + bfHi(wp.y) * z3;
    }
    size_t off = (size_t)node * DIM + lane;
    o1[off] = (u16)f2bf(a1);
    o2[off] = (u16)f2bf(a2);
    o0[off] = (u16)f2bf(a0);
    accFbf[off] = (u16)f2bf(bfLo((uint32)accFbf[off]) + a0);
}

// gather batch rows of both views (wave per row)
__global__ void k_gatherB(const int* __restrict__ nodes, const u16* __restrict__ t1,
                          const u16* __restrict__ t2, const u16* __restrict__ ebf,
                          float* __restrict__ accB1, float* __restrict__ accB2,
                          int init) {
    int t = blockIdx.x * blockDim.x + threadIdx.x;
    int b = t >> 6, lane = t & 63;
    int nd = nodes[b];
    size_t src = (size_t)nd * DIM + lane;
    size_t off = (size_t)b * DIM + lane;
    float x1 = bfLo((uint32)t1[src]);
    float x2 = bfLo((uint32)t2[src]);
    if (init) {
        float em = bfLo((uint32)ebf[src]);
        accB1[off] = em + x1;
        accB2[off] = em + x2;
    } else {
        accB1[off] += x1;
        accB2[off] += x2;
    }
}

// final gather + l1 normalize + pos score (wave per row)
__global__ void k_gnorm(const int* __restrict__ nodes, const u16* __restrict__ t1,
                        const u16* __restrict__ t2, const float* __restrict__ accB1,
                        const float* __restrict__ accB2, u16* __restrict__ n1b,
                        u16* __restrict__ n2b, float* __restrict__ pos) {
    int t = blockIdx.x * blockDim.x + threadIdx.x;
    int b = t >> 6, lane = t & 63;
    int nd = nodes[b];
    size_t src = (size_t)nd * DIM + lane;
    size_t off = (size_t)b * DIM + lane;
    float a = accB1[off] + bfLo((uint32)t1[src]);
    float c = accB2[off] + bfLo((uint32)t2[src]);
    float sa = waveSum(fabsf(a));
    float sc = waveSum(fabsf(c));
    float na = a / fmaxf(sa, 1e-12f);
    float nc = c / fmaxf(sc, 1e-12f);
    n1b[off] = (u16)f2bf(na);
    n2b[off] = (u16)f2bf(nc);
    float p = waveSum(na * nc);
    if (lane == 0) pos[b] = p;
}

// ---------------- SSL (MFMA) ----------------
#define SSL_JQ 8
__global__ __launch_bounds__(256) void k_ssl(const u16* __restrict__ n1b,
                                             const u16* __restrict__ n2b,
                                             float* __restrict__ ttl) {
    __shared__ u16 tile[128 * DIM];   // 16KB, XOR-swizzled
    int ib = blockIdx.x & 127;
    int jq = blockIdx.x >> 7;
    int wv = threadIdx.x >> 6, lane = threadIdx.x & 63;
    int i0 = ib * 64 + wv * 16;
    int r = lane & 15, g = lane >> 4;
    s16x8 a0 = *(const s16x8*)&n1b[(size_t)(i0 + r) * DIM + g * 8];
    s16x8 a1 = *(const s16x8*)&n1b[(size_t)(i0 + r) * DIM + 32 + g * 8];
    f32x4 sume = {0.f, 0.f, 0.f, 0.f};
    int j0 = jq * (BATCH / SSL_JQ);
    for (int jt = 0; jt < BATCH / SSL_JQ; jt += 128) {
        __syncthreads();
        for (int q = threadIdx.x; q < 1024; q += 256) {
            int row = q >> 3, ch = q & 7;
            uint4 src = *(const uint4*)&n2b[(size_t)(j0 + jt + row) * DIM + ch * 8];
            int dst = row * 128 + ((ch * 16) ^ ((row & 7) << 4));
            *(uint4*)((char*)tile + dst) = src;
        }
        __syncthreads();
#pragma unroll
        for (int tj = 0; tj < 8; ++tj) {
            int jr = tj * 16 + r;
            const char* base = (const char*)tile + jr * 128;
            int sw = (jr & 7) << 4;
            s16x8 b0 = *(const s16x8*)(base + ((g * 16) ^ sw));
            s16x8 b1 = *(const s16x8*)(base + (((4 + g) * 16) ^ sw));
            f32x4 d = {0.f, 0.f, 0.f, 0.f};
            d = __builtin_amdgcn_mfma_f32_16x16x32_bf16(a0, b0, d, 0, 0, 0);
            d = __builtin_amdgcn_mfma_f32_16x16x32_bf16(a1, b1, d, 0, 0, 0);
            sume.x += __expf(d.x * INV_T);
            sume.y += __expf(d.y * INV_T);
            sume.z += __expf(d.z * INV_T);
            sume.w += __expf(d.w * INV_T);
        }
    }
#pragma unroll
    for (int m = 1; m < 16; m <<= 1) {
        sume.x += __shfl_xor(sume.x, m, 64);
        sume.y += __shfl_xor(sume.y, m, 64);
        sume.z += __shfl_xor(sume.z, m, 64);
        sume.w += __shfl_xor(sume.w, m, 64);
    }
    if (r == 0) {
        atomicAdd(&ttl[i0 + g * 4 + 0], sume.x);
        atomicAdd(&ttl[i0 + g * 4 + 1], sume.y);
        atomicAdd(&ttl[i0 + g * 4 + 2], sume.z);
        atomicAdd(&ttl[i0 + g * 4 + 3], sume.w);
    }
}

__global__ void k_sslfin(const float* __restrict__ ttl, const float* __restrict__ pos,
                         float* __restrict__ accums) {
    int i = blockIdx.x * blockDim.x + threadIdx.x;
    float v = logf(ttl[i]) - pos[i] * INV_T;
    v = waveSum(v);
    __shared__ float red[4];
    int lane = threadIdx.x & 63, w = threadIdx.x >> 6;
    if (lane == 0) red[w] = v;
    __syncthreads();
    if (threadIdx.x == 0) atomicAdd(&accums[0], red[0] + red[1] + red[2] + red[3]);
}

// ---------------- BPR: quarter-wave per triple; per-block partials, NO atomics ----
__global__ __launch_bounds__(256) void k_bpr(const uint32* __restrict__ accFbf,
                                             const float* __restrict__ sqn,
                                             const int* __restrict__ nl,
                                             const int* __restrict__ pl,
                                             const int* __restrict__ ngl,
                                             float2* __restrict__ partials, int p) {
    int lane = threadIdx.x & 63;
    int q = lane >> 4, li = lane & 15;
    int wvb = threadIdx.x >> 6;
    int wv = blockIdx.x * 4 + wvb;
    int nw = gridDim.x * 4;
    const uint2* tab = (const uint2*)accFbf;
    float bprsum = 0.f, regsum = 0.f;
    for (int t0 = wv * 4 + q; t0 < p; t0 += nw * 4) {
        int a = nl[t0], b = pl[t0], c = ngl[t0];
        uint2 uu = tab[(size_t)a * 16 + li];
        uint2 vv = tab[(size_t)b * 16 + li];
        uint2 gg = tab[(size_t)c * 16 + li];
        float pd = bfLo(uu.x) * bfLo(vv.x) + bfHi(uu.x) * bfHi(vv.x)
                 + bfLo(uu.y) * bfLo(vv.y) + bfHi(uu.y) * bfHi(vv.y);
        float nd = bfLo(uu.x) * bfLo(gg.x) + bfHi(uu.x) * bfHi(gg.x)
                 + bfLo(uu.y) * bfLo(gg.y) + bfHi(uu.y) * bfHi(gg.y);
#pragma unroll
        for (int m = 1; m < 16; m <<= 1) {
            pd += __shfl_xor(pd, m, 64);
            nd += __shfl_xor(nd, m, 64);
        }
        if (li == 0) {
            float x = (nd - pd) * (1.0f / 16.0f);   // fold (1/4)^2 layer-mean
            float sp = fmaxf(x, 0.f) + log1pf(__expf(-fabsf(x)));
            bprsum += sp;
            regsum += sqn[a] + sqn[b] + sqn[c];
        }
    }
    bprsum = waveSum(bprsum);
    regsum = waveSum(regsum);
    __shared__ float2 red[4];
    if (lane == 0) red[wvb] = make_float2(bprsum, regsum);
    __syncthreads();
    if (threadIdx.x == 0) {
        float2 r0 = red[0], r1 = red[1], r2 = red[2], r3 = red[3];
        partials[blockIdx.x] = make_float2(r0.x + r1.x + r2.x + r3.x,
                                           r0.y + r1.y + r2.y + r3.y);
    }
}

// reduce BPR partials + combine all loss terms
__global__ __launch_bounds__(256) void k_final(const float2* __restrict__ partials,
                                               const float* __restrict__ accums,
                                               float* __restrict__ out) {
    float bs = 0.f, rs = 0.f;
    for (int i = threadIdx.x; i < BPR_BLOCKS; i += 256) {
        float2 v = partials[i];
        bs += v.x;
        rs += v.y;
    }
    bs = waveSum(bs);
    rs = waveSum(rs);
    __shared__ float2 red[4];
    int lane = threadIdx.x & 63, wv = threadIdx.x >> 6;
    if (lane == 0) red[wv] = make_float2(bs, rs);
    __syncthreads();
    if (threadIdx.x == 0) {
        float bpr = (red[0].x + red[1].x + red[2].x + red[3].x) * (1.0f / (float)NP);
        float reg = 0.5f * (red[0].y + red[1].y + red[2].y + red[3].y)
                  * (1.0f / (float)BATCH);
        out[0] = accums[0] + bpr + LAM_REG * reg;
    }
}

// ---------------- launch ----------------
extern "C" void kernel_launch(void* const* d_in, const int* in_sizes, int n_in,
                              void* d_out, int out_size, void* d_ws, size_t ws_size,
                              hipStream_t stream) {
    (void)in_sizes; (void)n_in; (void)out_size; (void)ws_size;
    const float* emb   = (const float*)d_in[0];
    const float* vals1 = (const float*)d_in[1];
    const float* vals2 = (const float*)d_in[2];
    const float* vals0 = (const float*)d_in[3];
    const int* erow    = (const int*)d_in[4];
    const int* ecol    = (const int*)d_in[5];
    const int* nodes   = (const int*)d_in[6];
    const int* nl      = (const int*)d_in[7];
    const int* pl      = (const int*)d_in[8];
    const int* ngl     = (const int*)d_in[9];
    float* out = (float*)d_out;

    char* w = (char*)d_ws;
    size_t off = 0;
    auto alloc = [&](size_t bytes) -> void* {
        void* p = w + off;
        off = (off + bytes + 255) & ~(size_t)255;
        return p;
    };
    int*    counts   = (int*)alloc((size_t)N_NODES * 4);
    int*    rowptr   = (int*)alloc((size_t)(N_NODES + 1) * 4);
    int*    bsums    = (int*)alloc(512);
    int*    ccol     = (int*)alloc((size_t)N_EPAD * 4);
    uint32* cw12     = (uint32*)alloc((size_t)N_EPAD * 4);
    u16*    cw0      = (u16*)alloc((size_t)N_EPAD * 2);
    u16*    ebf      = (u16*)alloc((size_t)N_NODES * DIM * 2);
    float*  sqn      = (float*)alloc((size_t)N_NODES * 4);
    u16*    A1       = (u16*)alloc((size_t)N_NODES * DIM * 2);
    u16*    A2       = (u16*)alloc((size_t)N_NODES * DIM * 2);
    u16*    A0       = (u16*)alloc((size_t)N_NODES * DIM * 2);
    u16*    B1       = (u16*)alloc((size_t)N_NODES * DIM * 2);
    u16*    B2       = (u16*)alloc((size_t)N_NODES * DIM * 2);
    u16*    B0       = (u16*)alloc((size_t)N_NODES * DIM * 2);
    u16*    accFbf   = (u16*)alloc((size_t)N_NODES * DIM * 2);
    float*  accB1    = (float*)alloc((size_t)BATCH * DIM * 4);
    float*  accB2    = (float*)alloc((size_t)BATCH * DIM * 4);
    u16*    n1b      = (u16*)alloc((size_t)BATCH * DIM * 2);
    u16*    n2b      = (u16*)alloc((size_t)BATCH * DIM * 2);
    float*  pos      = (float*)alloc((size_t)BATCH * 4);
    float*  ttl      = (float*)alloc((size_t)BATCH * 4);
    float*  accums   = (float*)alloc(256);
    float2* partials = (float2*)alloc((size_t)BPR_BLOCKS * 8);

    hipMemsetAsync(counts, 0, (size_t)N_NODES * 4, stream);
    hipMemsetAsync(ttl, 0, (size_t)BATCH * 4, stream);
    hipMemsetAsync(accums, 0, 256, stream);
    // zero edge arrays so pad slots contribute w=0 edges at col 0
    hipMemsetAsync(ccol, 0, (size_t)N_EPAD * 4, stream);
    hipMemsetAsync(cw12, 0, (size_t)N_EPAD * 4, stream);
    hipMemsetAsync(cw0, 0, (size_t)N_EPAD * 2, stream);

    // CSR build (padded)
    k_hist<<<N_EDGES / 256, 256, 0, stream>>>(erow, counts, N_EDGES);
    k_scan1<<<NB_SCAN, SCAN_CHUNK, 0, stream>>>(counts, rowptr, bsums, N_NODES);
    k_scan2<<<1, 128, 0, stream>>>(bsums, NB_SCAN, rowptr, N_NODES);
    k_scan3<<<NB_SCAN, SCAN_CHUNK, 0, stream>>>(rowptr, bsums, N_NODES);
    hipMemsetAsync(counts, 0, (size_t)N_NODES * 4, stream);
    k_scatter<<<N_EDGES / 256, 256, 0, stream>>>(erow, ecol, vals1, vals2, vals0,
                                                 rowptr, counts, ccol, cw12, cw0,
                                                 N_EDGES);
    k_cvtsq<<<N_NODES / 4, 256, 0, stream>>>(emb, ebf, sqn);

    const int propGrid = N_NODES / 4;   // wave per node, 4 waves/block
    const int gGrid = BATCH / 4;

    k_prop_l1<<<propGrid, 256, 0, stream>>>(rowptr, ccol, cw12, cw0, ebf,
                                            A1, A2, A0, accFbf);
    k_gatherB<<<gGrid, 256, 0, stream>>>(nodes, A1, A2, ebf, accB1, accB2, 1);
    k_prop_l23<<<propGrid, 256, 0, stream>>>(rowptr, ccol, cw12, cw0, A1, A2, A0,
                                             B1, B2, B0, accFbf);
    k_gatherB<<<gGrid, 256, 0, stream>>>(nodes, B1, B2, ebf, accB1, accB2, 0);
    k_prop_l23<<<propGrid, 256, 0, stream>>>(rowptr, ccol, cw12, cw0, B1, B2, B0,
                                             A1, A2, A0, accFbf);
    k_gnorm<<<gGrid, 256, 0, stream>>>(nodes, A1, A2, accB1, accB2, n1b, n2b, pos);

    // SSL
    k_ssl<<<(BATCH / 64) * SSL_JQ, 256, 0, stream>>>(n1b, n2b, ttl);
    k_sslfin<<<BATCH / 256, 256, 0, stream>>>(ttl, pos, accums);

    // BPR + reg (no atomics; per-block partials)
    k_bpr<<<BPR_BLOCKS, 256, 0, stream>>>((const uint32*)accFbf, sqn, nl, pl, ngl,
                                          partials, NP);

    k_final<<<1, 256, 0, stream>>>(partials, accums, out);
}